// Round 9
// baseline (205.185 us; speedup 1.0000x reference)
//
#include <hip/hip_runtime.h>

#define N_CLAUSES 50000
#define FEAT_DIM 64
#define EMBED_DIM 128
#define NUM_QUEUES 8
#define NUM_STEPS 2048
#define ENTROPY_COEF 0.1f

#define NCH 4            // chunks per step row
#define WPR 12500        // words per row (4 clauses/word, both mask dtypes)
#define WPC 3125         // words per chunk = WPR/NCH

typedef unsigned int v4u __attribute__((ext_vector_type(4)));

// ---------------- workspace layout (float units) ----------------
#define WS_LOGITS 0                 // [8][50000]
#define WS_ROWMAX 400000            // [8] int-encoded max
#define WS_K2T    400008            // [128][8]
#define WS_CQ     401032            // [8]
#define WS_W1T    401040            // [128][64]
#define WS_PART   409248            // [2048][4] float4 (16B aligned)
#define WS_LOSS   (WS_PART + NUM_STEPS * NCH * 4)   // [2048]

// order-preserving float<->int encode for atomicMax on signed int
__device__ inline int enc_f(float f) {
  int b = __float_as_int(f);
  return b >= 0 ? b : (b ^ 0x7FFFFFFF);
}
__device__ inline float dec_f(int k) {
  return __int_as_float(k >= 0 ? k : (k ^ 0x7FFFFFFF));
}

__global__ __launch_bounds__(1024) void k_prep(const float* __restrict__ W1,
    const float* __restrict__ b2, const float* __restrict__ W2,
    const float* __restrict__ keys, float* __restrict__ W1T,
    float* __restrict__ K2T, float* __restrict__ cq, int* __restrict__ rowmax_i) {
  int tid = threadIdx.x;
  {
    int q = tid >> 7, j = tid & 127;
    float a = 0.f;
    for (int e = 0; e < EMBED_DIM; ++e)
      a = fmaf(W2[j * EMBED_DIM + e], keys[q * EMBED_DIM + e], a);
    K2T[j * 8 + q] = a;
  }
  if (tid < NUM_QUEUES) {
    float a = 0.f;
    for (int e = 0; e < EMBED_DIM; ++e)
      a = fmaf(b2[e], keys[tid * EMBED_DIM + e], a);
    cq[tid] = a;
    rowmax_i[tid] = (int)0x80000000;   // INT_MIN
  }
  for (int i = tid; i < FEAT_DIM * EMBED_DIM; i += 1024) {
    int j = i >> 6, f = i & 63;
    W1T[j * 64 + f] = W1[f * EMBED_DIM + j];
  }
}

// logits[q][n] = relu(fv[n]@W1 + b1) . K2[q] + cq[q]; fused per-queue row-max.
__global__ __launch_bounds__(256) void k_logits(const float* __restrict__ fv,
    const float* __restrict__ b1, const float* __restrict__ W1T,
    const float* __restrict__ K2T, const float* __restrict__ cq,
    float* __restrict__ logits, int* __restrict__ rowmax_i) {
  int t = threadIdx.x;
  int n = blockIdx.x * 256 + t;
  bool act = n < N_CLAUSES;
  int nn = act ? n : (N_CLAUSES - 1);
  float r[FEAT_DIM];
  const float4* fp = (const float4*)(fv + (size_t)nn * FEAT_DIM);
#pragma unroll
  for (int i = 0; i < FEAT_DIM / 4; ++i) {
    float4 v = fp[i];
    r[4 * i] = v.x; r[4 * i + 1] = v.y; r[4 * i + 2] = v.z; r[4 * i + 3] = v.w;
  }
  float acc[NUM_QUEUES];
#pragma unroll
  for (int q = 0; q < NUM_QUEUES; ++q) acc[q] = cq[q];
#pragma unroll 4
  for (int j = 0; j < EMBED_DIM; ++j) {
    const float* w = W1T + j * 64;   // wave-uniform -> scalar loads
    float t0 = 0.f, t1 = 0.f, t2 = 0.f, t3 = 0.f;
#pragma unroll
    for (int f = 0; f < FEAT_DIM; f += 4) {
      t0 = fmaf(r[f],     w[f],     t0);
      t1 = fmaf(r[f + 1], w[f + 1], t1);
      t2 = fmaf(r[f + 2], w[f + 2], t2);
      t3 = fmaf(r[f + 3], w[f + 3], t3);
    }
    float tt = fmaxf((t0 + t1) + (t2 + t3) + b1[j], 0.f);
    const float* k2 = K2T + j * 8;
#pragma unroll
    for (int q = 0; q < NUM_QUEUES; ++q) acc[q] = fmaf(tt, k2[q], acc[q]);
  }
  if (act) {
#pragma unroll
    for (int q = 0; q < NUM_QUEUES; ++q)
      logits[(size_t)q * N_CLAUSES + n] = acc[q];
  }
  __shared__ float sred[4][8];
  float red[NUM_QUEUES];
#pragma unroll
  for (int q = 0; q < NUM_QUEUES; ++q) {
    float m = acc[q];   // inactive lanes duplicate clause 49999 (harmless for max)
#pragma unroll
    for (int o = 32; o > 0; o >>= 1) m = fmaxf(m, __shfl_xor(m, o, 64));
    red[q] = m;
  }
  if ((t & 63) == 0) {
    int w = t >> 6;
#pragma unroll
    for (int q = 0; q < NUM_QUEUES; ++q) sred[w][q] = red[q];
  }
  __syncthreads();
  if (t < NUM_QUEUES) {
    float m = fmaxf(fmaxf(sred[0][t], sred[1][t]), fmaxf(sred[2][t], sred[3][t]));
    atomicMax(&rowmax_i[t], enc_f(m));
  }
}

// Block (s, c): 12500/4 words of step s's mask row + matching logits.
// Word = 4 clauses in BOTH mask dtypes (u32 of 4 bytes, or uint4 of 4 ints).
// All loads coalesced (word-per-lane); NO nontemporal (keep mask L3-resident
// across graph replays). Each block covers ALL its chunk's clauses (every wave
// sums a lane-contiguous quarter; block-level LDS combine before the write).
__global__ __launch_bounds__(256) void k_step(const float* __restrict__ logits,
    const int* __restrict__ rowmax_i, const void* __restrict__ maskv,
    const int* __restrict__ qi, float4* __restrict__ part) {
  int s = blockIdx.x, c = blockIdx.y, t = threadIdx.x;
  // self-detect mask dtype from first 1024 words (L2-hot; per-wave __any)
  const unsigned* mw0 = (const unsigned*)maskv;
  bool bytemask = __any((mw0[t] > 1u) | (mw0[t + 256] > 1u) |
                        (mw0[t + 512] > 1u) | (mw0[t + 768] > 1u));
  int q = qi[s];
  float M = dec_f(rowmax_i[q]);
  const float4* lrow4 = (const float4*)(logits + (size_t)q * N_CLAUSES) + c * WPC;
  float z = 0.f, s1 = 0.f, cc = 0.f;

  if (bytemask) {
    const unsigned* mrow =
        (const unsigned*)((const unsigned char*)maskv + (size_t)s * N_CLAUSES) + c * WPC;
    auto body = [&](int idx) {
      unsigned m = mrow[idx];
      float4 l = lrow4[idx];
      float b0 = (m & 0x000000ffu) ? 1.f : 0.f;
      float b1 = (m & 0x0000ff00u) ? 1.f : 0.f;
      float b2 = (m & 0x00ff0000u) ? 1.f : 0.f;
      float b3 = (m & 0xff000000u) ? 1.f : 0.f;
      float a0 = l.x - M, a1 = l.y - M, a2 = l.z - M, a3 = l.w - M;
      float e0 = __expf(a0), e1 = __expf(a1), e2 = __expf(a2), e3 = __expf(a3);
      z  = fmaf(b0, e0, z);       z  = fmaf(b1, e1, z);
      z  = fmaf(b2, e2, z);       z  = fmaf(b3, e3, z);
      s1 = fmaf(b0, e0 * a0, s1); s1 = fmaf(b1, e1 * a1, s1);
      s1 = fmaf(b2, e2 * a2, s1); s1 = fmaf(b3, e3 * a3, s1);
      cc += (b0 + b1) + (b2 + b3);
    };
#pragma unroll 4
    for (int i = 0; i < 12; ++i) body(i * 256 + t);
    if (t < WPC - 12 * 256) body(12 * 256 + t);        // tail: t < 53
  } else {
    const v4u* mrow = (const v4u*)((const int*)maskv + (size_t)s * N_CLAUSES) + c * WPC;
    auto body = [&](int idx) {
      v4u m = mrow[idx];
      float4 l = lrow4[idx];
      float b0 = m.x ? 1.f : 0.f;
      float b1 = m.y ? 1.f : 0.f;
      float b2 = m.z ? 1.f : 0.f;
      float b3 = m.w ? 1.f : 0.f;
      float a0 = l.x - M, a1 = l.y - M, a2 = l.z - M, a3 = l.w - M;
      float e0 = __expf(a0), e1 = __expf(a1), e2 = __expf(a2), e3 = __expf(a3);
      z  = fmaf(b0, e0, z);       z  = fmaf(b1, e1, z);
      z  = fmaf(b2, e2, z);       z  = fmaf(b3, e3, z);
      s1 = fmaf(b0, e0 * a0, s1); s1 = fmaf(b1, e1 * a1, s1);
      s1 = fmaf(b2, e2 * a2, s1); s1 = fmaf(b3, e3 * a3, s1);
      cc += (b0 + b1) + (b2 + b3);
    };
#pragma unroll 4
    for (int i = 0; i < 12; ++i) body(i * 256 + t);
    if (t < WPC - 12 * 256) body(12 * 256 + t);
  }

#pragma unroll
  for (int o = 32; o > 0; o >>= 1) {
    z += __shfl_xor(z, o, 64);
    s1 += __shfl_xor(s1, o, 64);
    cc += __shfl_xor(cc, o, 64);
  }
  __shared__ float sZ[4], sS[4], sC[4];
  int w = t >> 6;
  if ((t & 63) == 0) { sZ[w] = z; sS[w] = s1; sC[w] = cc; }
  __syncthreads();
  if (t == 0) {
    part[(size_t)s * NCH + c] = make_float4(sZ[0] + sZ[1] + sZ[2] + sZ[3],
                                            sS[0] + sS[1] + sS[2] + sS[3],
                                            sC[0] + sC[1] + sC[2] + sC[3], 0.f);
  }
}

// one thread per step: combine 4 chunk partials, finish per-step loss
__global__ __launch_bounds__(256) void k_red(const float4* __restrict__ part,
    const float* __restrict__ logits, const int* __restrict__ rowmax_i,
    const float* __restrict__ rewards, const int* __restrict__ qi,
    const int* __restrict__ si, float* __restrict__ loss) {
  int s = blockIdx.x * 256 + threadIdx.x;
  float4 p0 = part[(size_t)s * NCH + 0];
  float4 p1 = part[(size_t)s * NCH + 1];
  float4 p2 = part[(size_t)s * NCH + 2];
  float4 p3 = part[(size_t)s * NCH + 3];
  float z = (p0.x + p1.x) + (p2.x + p3.x);
  float s1 = (p0.y + p1.y) + (p2.y + p3.y);
  float c = (p0.z + p1.z) + (p2.z + p3.z);
  int q = qi[s];
  float M = dec_f(rowmax_i[q]);
  float ssel = logits[(size_t)q * N_CLAUSES + si[s]];
  float logZ = logf(z);
  float ce = logZ - (ssel - M);            // = -log_softmax[sel]
  float me = (s1 / z - logZ) / logf(c);    // normalized minus-entropy
  loss[s] = rewards[s] * ce + ENTROPY_COEF * me;
}

__global__ __launch_bounds__(256) void k_sum(const float* __restrict__ loss,
                                             float* __restrict__ out) {
  int tid = threadIdx.x;
  float v = 0.f;
  for (int i = tid; i < NUM_STEPS; i += 256) v += loss[i];
#pragma unroll
  for (int o = 32; o > 0; o >>= 1) v += __shfl_xor(v, o, 64);
  __shared__ float sv[4];
  if ((tid & 63) == 0) sv[tid >> 6] = v;
  __syncthreads();
  if (tid == 0) out[0] = sv[0] + sv[1] + sv[2] + sv[3];
}

extern "C" void kernel_launch(void* const* d_in, const int* in_sizes, int n_in,
                              void* d_out, int out_size, void* d_ws, size_t ws_size,
                              hipStream_t stream) {
  const float* fv      = (const float*)d_in[0];
  const float* W1      = (const float*)d_in[1];
  const float* b1      = (const float*)d_in[2];
  const float* W2      = (const float*)d_in[3];
  const float* b2      = (const float*)d_in[4];
  const float* keys    = (const float*)d_in[5];
  const float* rewards = (const float*)d_in[6];
  const void*  mask    = d_in[7];
  const int*   queue_i = (const int*)d_in[8];
  const int*   sel_i   = (const int*)d_in[9];
  float* out = (float*)d_out;
  float* ws  = (float*)d_ws;

  float*  logits   = ws + WS_LOGITS;
  int*    rowmax_i = (int*)(ws + WS_ROWMAX);
  float*  K2T      = ws + WS_K2T;
  float*  cq       = ws + WS_CQ;
  float*  W1T      = ws + WS_W1T;
  float4* part     = (float4*)(ws + WS_PART);
  float*  loss     = ws + WS_LOSS;

  hipLaunchKernelGGL(k_prep, dim3(1), dim3(1024), 0, stream,
                     W1, b2, W2, keys, W1T, K2T, cq, rowmax_i);
  hipLaunchKernelGGL(k_logits, dim3((N_CLAUSES + 255) / 256), dim3(256), 0, stream,
                     fv, b1, W1T, K2T, cq, logits, rowmax_i);
  hipLaunchKernelGGL(k_step, dim3(NUM_STEPS, NCH), dim3(256), 0, stream,
                     logits, rowmax_i, mask, queue_i, part);
  hipLaunchKernelGGL(k_red, dim3(NUM_STEPS / 256), dim3(256), 0, stream,
                     part, logits, rowmax_i, rewards, queue_i, sel_i, loss);
  hipLaunchKernelGGL(k_sum, dim3(1), dim3(256), 0, stream, loss, out);
}